// Round 3
// baseline (47.418 us; speedup 1.0000x reference)
//
#include <hip/hip_runtime.h>
#include <hip/hip_bf16.h>

// Problem constants (from reference)
#define VOCAB   128000
#define DIM     2048
#define N_TRAIN 256
#define N_TOKENS (4 * 4096)   // BATCH * SEQ

typedef float f32x4 __attribute__((ext_vector_type(4)));

// One block per output token row. 256 threads.
// out[row, :] = W[t, :] + sum over k with token_indices[k]==t of delta_rows[k, :]
// delta layout (COO column-major): delta_rows[k][c] = delta[c * N_TRAIN + k]
__global__ __launch_bounds__(256) void gather_adapted_rows(
    const int* __restrict__ x,          // [N_TOKENS] token ids
    const float* __restrict__ W,        // [VOCAB, DIM]
    const float* __restrict__ delta,    // [DIM * N_TRAIN], col-major over (k, c)
    const int* __restrict__ tok_idx,    // [N_TRAIN]
    float* __restrict__ out)            // [N_TOKENS, DIM]
{
    __shared__ int s_match_k[N_TRAIN];
    __shared__ int s_nmatch;

    const int row = blockIdx.x;
    const int tid = threadIdx.x;
    const int t = x[row];   // broadcast scalar load

    if (tid == 0) s_nmatch = 0;
    __syncthreads();

    // 256 threads each check one trained-token slot (handles duplicate
    // trained tokens correctly: every matching k is accumulated).
    if (tok_idx[tid] == t) {
        int slot = atomicAdd(&s_nmatch, 1);
        s_match_k[slot] = tid;
    }
    __syncthreads();

    const int nm = s_nmatch;
    const f32x4* __restrict__ wrow4 =
        reinterpret_cast<const f32x4*>(W + (size_t)t * DIM);
    f32x4* __restrict__ orow4 =
        reinterpret_cast<f32x4*>(out + (size_t)row * DIM);

    // 2048 floats / 256 threads = 2 float4 per thread; issue BOTH loads
    // before any dependent work so two 16B loads are in flight per thread.
    const int f4a = tid;          // 0..255
    const int f4b = tid + 256;    // 256..511
    f32x4 v0 = wrow4[f4a];
    f32x4 v1 = wrow4[f4b];

    // Rare path (~33 of 16384 rows): accumulate matched delta rows.
    if (nm > 0) {
        for (int m = 0; m < nm; ++m) {
            const int k = s_match_k[m];
            const int ca = f4a * 4;
            v0.x += delta[(size_t)(ca + 0) * N_TRAIN + k];
            v0.y += delta[(size_t)(ca + 1) * N_TRAIN + k];
            v0.z += delta[(size_t)(ca + 2) * N_TRAIN + k];
            v0.w += delta[(size_t)(ca + 3) * N_TRAIN + k];
            const int cb = f4b * 4;
            v1.x += delta[(size_t)(cb + 0) * N_TRAIN + k];
            v1.y += delta[(size_t)(cb + 1) * N_TRAIN + k];
            v1.z += delta[(size_t)(cb + 2) * N_TRAIN + k];
            v1.w += delta[(size_t)(cb + 3) * N_TRAIN + k];
        }
    }

    // Non-temporal: out is write-once, never re-read — keep it out of L2/L3
    // so duplicate-token W rows stay cached.
    __builtin_nontemporal_store(v0, &orow4[f4a]);
    __builtin_nontemporal_store(v1, &orow4[f4b]);
}

extern "C" void kernel_launch(void* const* d_in, const int* in_sizes, int n_in,
                              void* d_out, int out_size, void* d_ws, size_t ws_size,
                              hipStream_t stream) {
    const int*   x       = (const int*)  d_in[0];  // [16384]
    const float* W       = (const float*)d_in[1];  // [128000*2048]
    const float* delta   = (const float*)d_in[2];  // [2048*256]
    const int*   tok_idx = (const int*)  d_in[3];  // [256]
    float* out = (float*)d_out;

    dim3 grid(N_TOKENS);
    dim3 block(256);
    gather_adapted_rows<<<grid, block, 0, stream>>>(x, W, delta, tok_idx, out);
}

// Round 4
// 46.695 us; speedup vs baseline: 1.0155x; 1.0155x over previous
//
#include <hip/hip_runtime.h>
#include <hip/hip_bf16.h>

// Problem constants (from reference)
#define VOCAB   128000
#define DIM     2048
#define N_TRAIN 256
#define N_TOKENS (4 * 4096)   // BATCH * SEQ

typedef float f32x4 __attribute__((ext_vector_type(4)));

// One block (256 threads, 4 waves) per output token row.
// out[row, :] = W[t, :] + sum over k with token_indices[k]==t of delta_rows[k, :]
// delta layout (COO column-major): delta_rows[k][c] = delta[c * N_TRAIN + k]
//
// Barrier-free: W-row loads issue immediately after t resolves; the
// trained-token match runs under the load shadow via per-wave ballots
// (each wave redundantly checks all 256 slots — no LDS, no atomics).
__global__ __launch_bounds__(256) void gather_adapted_rows(
    const int* __restrict__ x,          // [N_TOKENS] token ids
    const float* __restrict__ W,        // [VOCAB, DIM]
    const float* __restrict__ delta,    // [DIM * N_TRAIN], col-major over (k, c)
    const int* __restrict__ tok_idx,    // [N_TRAIN]
    float* __restrict__ out)            // [N_TOKENS, DIM]
{
    const int row = blockIdx.x;
    const int tid = threadIdx.x;
    const int lane = tid & 63;

    const int t = x[row];   // uniform scalar load (SGPR)

    // Issue both 16B W-row loads NOW — everything below overlaps their latency.
    const f32x4* __restrict__ wrow4 =
        reinterpret_cast<const f32x4*>(W + (size_t)t * DIM);
    const int f4a = tid;          // 0..255
    const int f4b = tid + 256;    // 256..511
    f32x4 v0 = wrow4[f4a];
    f32x4 v1 = wrow4[f4b];

    // Per-wave match of all 256 trained-token slots: 4 ballots.
    // Bit l of mask[j] set  <=>  tok_idx[64*j + l] == t.
    unsigned long long m0 = __ballot(tok_idx[lane      ] == t);
    unsigned long long m1 = __ballot(tok_idx[lane +  64] == t);
    unsigned long long m2 = __ballot(tok_idx[lane + 128] == t);
    unsigned long long m3 = __ballot(tok_idx[lane + 192] == t);

    // Rare path (~33 of 16384 rows): accumulate every matched delta row k.
    if (m0 | m1 | m2 | m3) {
        unsigned long long masks[4] = {m0, m1, m2, m3};
        #pragma unroll
        for (int j = 0; j < 4; ++j) {
            unsigned long long m = masks[j];
            while (m) {
                const int l = __builtin_ctzll(m);
                m &= m - 1;
                const int k = 64 * j + l;
                const int ca = f4a * 4;
                v0.x += delta[(size_t)(ca + 0) * N_TRAIN + k];
                v0.y += delta[(size_t)(ca + 1) * N_TRAIN + k];
                v0.z += delta[(size_t)(ca + 2) * N_TRAIN + k];
                v0.w += delta[(size_t)(ca + 3) * N_TRAIN + k];
                const int cb = f4b * 4;
                v1.x += delta[(size_t)(cb + 0) * N_TRAIN + k];
                v1.y += delta[(size_t)(cb + 1) * N_TRAIN + k];
                v1.z += delta[(size_t)(cb + 2) * N_TRAIN + k];
                v1.w += delta[(size_t)(cb + 3) * N_TRAIN + k];
            }
        }
    }

    f32x4* __restrict__ orow4 =
        reinterpret_cast<f32x4*>(out + (size_t)row * DIM);
    __builtin_nontemporal_store(v0, &orow4[f4a]);
    __builtin_nontemporal_store(v1, &orow4[f4b]);
}

extern "C" void kernel_launch(void* const* d_in, const int* in_sizes, int n_in,
                              void* d_out, int out_size, void* d_ws, size_t ws_size,
                              hipStream_t stream) {
    const int*   x       = (const int*)  d_in[0];  // [16384]
    const float* W       = (const float*)d_in[1];  // [128000*2048]
    const float* delta   = (const float*)d_in[2];  // [2048*256]
    const int*   tok_idx = (const int*)  d_in[3];  // [256]
    float* out = (float*)d_out;

    dim3 grid(N_TOKENS);
    dim3 block(256);
    gather_adapted_rows<<<grid, block, 0, stream>>>(x, W, delta, tok_idx, out);
}